// Round 1
// baseline (18175.174 us; speedup 1.0000x reference)
//
#include <hip/hip_runtime.h>

// Problem constants (reference: N=50000 nodes, E=800000 edges, D=128, K=3)
#define Nn 50000
#define Ee 800000
#define Dd 128
#define Kk 3
#define TE 128   // rows per block
#define NT 256   // threads per block

// Fused 2-layer MLP over TE rows:
//   out = act( relu( X[g] @ W1 + B1 ) @ W2 + B2 )
// mode 0: direct store (optional base add, sink-row zero, final relu)
// mode 1: relu + atomic scatter-add into Z[sidx[row]]
//
// LDS: single 64KB buffer, reused for input tile then hidden tile.
// Register tile: 8 rows x 8 cols per thread (64 fp32 acc).
// XOR swizzle on LDS column: concurrent lanes read rows {mg,mg+1,mg+2,mg+3}
// whose swizzled banks are k, k^8, k^16, k^24 -> 4 distinct banks.

#define GEMM_LAYER(Wmat)                                                \
  {                                                                     \
    _Pragma("unroll 4")                                                 \
    for (int k = 0; k < Dd; ++k) {                                      \
      const float4 wa = *(const float4*)(Wmat + k * Dd + n0);           \
      const float4 wb = *(const float4*)(Wmat + k * Dd + n0 + 4);       \
      _Pragma("unroll")                                                 \
      for (int i = 0; i < 8; ++i) {                                     \
        const float a = S[(mg + 16 * i) * Dd + (k ^ sw)];               \
        acc[i][0] = fmaf(a, wa.x, acc[i][0]);                           \
        acc[i][1] = fmaf(a, wa.y, acc[i][1]);                           \
        acc[i][2] = fmaf(a, wa.z, acc[i][2]);                           \
        acc[i][3] = fmaf(a, wa.w, acc[i][3]);                           \
        acc[i][4] = fmaf(a, wb.x, acc[i][4]);                           \
        acc[i][5] = fmaf(a, wb.y, acc[i][5]);                           \
        acc[i][6] = fmaf(a, wb.z, acc[i][6]);                           \
        acc[i][7] = fmaf(a, wb.w, acc[i][7]);                           \
      }                                                                 \
    }                                                                   \
  }

__global__ __launch_bounds__(NT) void mlp2_kernel(
    const float* __restrict__ X, const int* __restrict__ gidx, int nrows,
    const float* __restrict__ W1, const float* __restrict__ B1,
    const float* __restrict__ W2, const float* __restrict__ B2,
    int mode, float* __restrict__ out, int out_stride, int out_col,
    const float* __restrict__ base, int sink, int final_relu,
    const int* __restrict__ sidx, float* __restrict__ Z)
{
  __shared__ float S[TE * Dd];  // 64 KB exactly -> 2 blocks/CU
  const int t = threadIdx.x;
  const int row0 = blockIdx.x * TE;
  const int rem = nrows - row0;
  const int nrow = rem < TE ? rem : TE;

  // ---- stage (gathered) input rows into LDS, zero-fill OOB rows ----
  for (int i = t; i < TE * (Dd / 4); i += NT) {
    const int r = i >> 5;            // 32 float4 chunks per row
    const int c = (i & 31) << 2;
    float4 v = make_float4(0.f, 0.f, 0.f, 0.f);
    if (r < nrow) {
      const int g = gidx ? gidx[row0 + r] : (row0 + r);
      v = *(const float4*)(X + (size_t)g * Dd + c);
    }
    *(float4*)(&S[r * Dd + (c ^ ((r & 3) << 3))]) = v;
  }
  __syncthreads();

  const int ng = t & 15;          // col group: cols n0..n0+7
  const int mg = t >> 4;          // row group: rows mg+16*i, i=0..7
  const int n0 = ng * 8;
  const int sw = (mg & 3) << 3;   // LDS bank swizzle selector (row-derived)

  float acc[8][8];

  // ---- layer 1 ----
  #pragma unroll
  for (int i = 0; i < 8; ++i)
    #pragma unroll
    for (int j = 0; j < 8; ++j) acc[i][j] = 0.f;
  GEMM_LAYER(W1);
  __syncthreads();  // all reads of input tile done

  // bias + relu -> hidden tile into same LDS
  {
    const float4 b0 = *(const float4*)(B1 + n0);
    const float4 b1 = *(const float4*)(B1 + n0 + 4);
    #pragma unroll
    for (int i = 0; i < 8; ++i) {
      const int m = mg + 16 * i;
      float4 h0, h1;
      h0.x = fmaxf(acc[i][0] + b0.x, 0.f);
      h0.y = fmaxf(acc[i][1] + b0.y, 0.f);
      h0.z = fmaxf(acc[i][2] + b0.z, 0.f);
      h0.w = fmaxf(acc[i][3] + b0.w, 0.f);
      h1.x = fmaxf(acc[i][4] + b1.x, 0.f);
      h1.y = fmaxf(acc[i][5] + b1.y, 0.f);
      h1.z = fmaxf(acc[i][6] + b1.z, 0.f);
      h1.w = fmaxf(acc[i][7] + b1.w, 0.f);
      *(float4*)(&S[m * Dd + (n0 ^ sw)]) = h0;
      *(float4*)(&S[m * Dd + ((n0 + 4) ^ sw)]) = h1;
    }
  }
  __syncthreads();

  // ---- layer 2 ----
  #pragma unroll
  for (int i = 0; i < 8; ++i)
    #pragma unroll
    for (int j = 0; j < 8; ++j) acc[i][j] = 0.f;
  GEMM_LAYER(W2);

  const float4 c0 = *(const float4*)(B2 + n0);
  const float4 c1 = *(const float4*)(B2 + n0 + 4);

  if (mode == 1) {
    // relu(msg) -> atomic scatter-add into Z[dst]
    #pragma unroll
    for (int i = 0; i < 8; ++i) {
      const int r = mg + 16 * i;
      if (r < nrow) {
        const int dn = sidx[row0 + r];
        float* zp = Z + (size_t)dn * Dd + n0;
        float v[8];
        v[0] = fmaxf(acc[i][0] + c0.x, 0.f);
        v[1] = fmaxf(acc[i][1] + c0.y, 0.f);
        v[2] = fmaxf(acc[i][2] + c0.z, 0.f);
        v[3] = fmaxf(acc[i][3] + c0.w, 0.f);
        v[4] = fmaxf(acc[i][4] + c1.x, 0.f);
        v[5] = fmaxf(acc[i][5] + c1.y, 0.f);
        v[6] = fmaxf(acc[i][6] + c1.z, 0.f);
        v[7] = fmaxf(acc[i][7] + c1.w, 0.f);
        #pragma unroll
        for (int j = 0; j < 8; ++j) unsafeAtomicAdd(zp + j, v[j]);
      }
    }
  } else {
    #pragma unroll
    for (int i = 0; i < 8; ++i) {
      const int r = mg + 16 * i;
      if (r < nrow) {
        const int gr = row0 + r;
        float v[8];
        v[0] = acc[i][0] + c0.x; v[1] = acc[i][1] + c0.y;
        v[2] = acc[i][2] + c0.z; v[3] = acc[i][3] + c0.w;
        v[4] = acc[i][4] + c1.x; v[5] = acc[i][5] + c1.y;
        v[6] = acc[i][6] + c1.z; v[7] = acc[i][7] + c1.w;
        if (final_relu) {
          #pragma unroll
          for (int j = 0; j < 8; ++j) v[j] = fmaxf(v[j], 0.f);
        }
        if (base) {
          if (gr == sink) {
            #pragma unroll
            for (int j = 0; j < 8; ++j) v[j] = 0.f;  // h[sink] = 0
          }
          const float4 e0 = *(const float4*)(base + (size_t)gr * Dd + n0);
          const float4 e1 = *(const float4*)(base + (size_t)gr * Dd + n0 + 4);
          v[0] += e0.x; v[1] += e0.y; v[2] += e0.z; v[3] += e0.w;
          v[4] += e1.x; v[5] += e1.y; v[6] += e1.z; v[7] += e1.w;
        }
        float* op = out + (size_t)gr * out_stride + out_col + n0;
        float4 o0 = make_float4(v[0], v[1], v[2], v[3]);
        float4 o1 = make_float4(v[4], v[5], v[6], v[7]);
        *(float4*)op = o0;
        *(float4*)(op + 4) = o1;
      }
    }
  }
}

extern "C" void kernel_launch(void* const* d_in, const int* in_sizes, int n_in,
                              void* d_out, int out_size, void* d_ws, size_t ws_size,
                              hipStream_t stream)
{
  const float* feat = (const float*)d_in[0];
  const int*   src  = (const int*)d_in[1];
  const int*   dst  = (const int*)d_in[2];

  // d_in[3..22]: nt, fp, fu, bp, bu -- each (w1, b1, w2, b2)
  const float* W[5][4];
  for (int p = 0; p < 5; ++p)
    for (int q = 0; q < 4; ++q)
      W[p][q] = (const float*)d_in[3 + p * 4 + q];

  float* st  = (float*)d_ws;                    // self_trans  [N,D]
  float* y   = st + (size_t)Nn * Dd;            // y state     [N,D]
  float* z   = y  + (size_t)Nn * Dd;            // scatter acc [N,D]
  float* out = (float*)d_out;                   // [N, 2D]

  const int nodeBlocks = (Nn + TE - 1) / TE;    // 391
  const int edgeBlocks = (Ee + TE - 1) / TE;    // 6250

  // self_trans = fnn(feat; nt), no final relu
  mlp2_kernel<<<nodeBlocks, NT, 0, stream>>>(
      feat, nullptr, Nn,
      W[0][0], W[0][1], W[0][2], W[0][3],
      0, st, Dd, 0, nullptr, -1, 0, nullptr, nullptr);

  for (int dir = 0; dir < 2; ++dir) {
    const int* g = (dir == 0) ? src : dst;      // gather index
    const int* s = (dir == 0) ? dst : src;      // scatter index
    const int sink = (dir == 0) ? (Nn - 1) : 0;
    const float* const* P = W[(dir == 0) ? 1 : 3];  // edge MLP
    const float* const* U = W[(dir == 0) ? 2 : 4];  // node MLP
    const float* yin = st;
    for (int k = 0; k < Kk; ++k) {
      hipMemsetAsync(z, 0, (size_t)Nn * Dd * sizeof(float), stream);
      // msg = relu(fnn(y[g]; P)); z[s] += msg
      mlp2_kernel<<<edgeBlocks, NT, 0, stream>>>(
          yin, g, Ee,
          P[0], P[1], P[2], P[3],
          1, nullptr, 0, 0, nullptr, -1, 1, s, z);
      // y = self_trans + relu(fnn(z; U)), h[sink]=0; last round -> d_out
      const bool last = (k == Kk - 1);
      mlp2_kernel<<<nodeBlocks, NT, 0, stream>>>(
          z, nullptr, Nn,
          U[0], U[1], U[2], U[3],
          0, last ? out : y, last ? 2 * Dd : Dd, last ? (dir ? Dd : 0) : 0,
          st, sink, 1, nullptr, nullptr);
      yin = y;
    }
  }
}

// Round 2
// 4828.732 us; speedup vs baseline: 3.7640x; 3.7640x over previous
//
#include <hip/hip_runtime.h>

// Problem constants (reference: N=50000 nodes, E=800000 edges, D=128, K=3)
#define Nn 50000
#define Ee 800000
#define Dd 128
#define Kk 3
#define TE 128   // rows per block
#define NT 256   // threads per block

// ---------------------------------------------------------------------------
// Fused 2-layer MLP core (shared by node + edge kernels):
//   hidden = relu(X @ W1 + B1); out = hidden @ W2 + B2
// LDS: single 64KB tile reused for input rows, then hidden rows, then (edge
// kernel only) message rows. Register tile: 8 rows x 8 cols per thread.
// XOR swizzle on LDS column breaks the stride-128 bank collision: row r's
// element k lives at S[r*Dd + (k ^ ((r&3)<<3))].
// ---------------------------------------------------------------------------
#define GEMM_LAYER(Wmat)                                                \
  {                                                                     \
    _Pragma("unroll 4")                                                 \
    for (int k = 0; k < Dd; ++k) {                                      \
      const float4 wa = *(const float4*)(Wmat + k * Dd + n0);           \
      const float4 wb = *(const float4*)(Wmat + k * Dd + n0 + 4);       \
      _Pragma("unroll")                                                 \
      for (int i = 0; i < 8; ++i) {                                     \
        const float a = S[(mg + 16 * i) * Dd + (k ^ sw)];               \
        acc[i][0] = fmaf(a, wa.x, acc[i][0]);                           \
        acc[i][1] = fmaf(a, wa.y, acc[i][1]);                           \
        acc[i][2] = fmaf(a, wa.z, acc[i][2]);                           \
        acc[i][3] = fmaf(a, wa.w, acc[i][3]);                           \
        acc[i][4] = fmaf(a, wb.x, acc[i][4]);                           \
        acc[i][5] = fmaf(a, wb.y, acc[i][5]);                           \
        acc[i][6] = fmaf(a, wb.z, acc[i][6]);                           \
        acc[i][7] = fmaf(a, wb.w, acc[i][7]);                           \
      }                                                                 \
    }                                                                   \
  }

// ---------------------------------------------------------------------------
// Node-level MLP: out = [optional relu]( fnn(X) ) (+ base, sink-row zeroed)
// ---------------------------------------------------------------------------
__global__ __launch_bounds__(NT) void node_mlp_kernel(
    const float* __restrict__ X, int nrows,
    const float* __restrict__ W1, const float* __restrict__ B1,
    const float* __restrict__ W2, const float* __restrict__ B2,
    float* __restrict__ out, int out_stride, int out_col,
    const float* __restrict__ base, int sink, int final_relu)
{
  __shared__ float S[TE * Dd];  // 64 KB
  const int t = threadIdx.x;
  const int row0 = blockIdx.x * TE;
  const int rem = nrows - row0;
  const int nrow = rem < TE ? rem : TE;

  for (int i = t; i < TE * (Dd / 4); i += NT) {
    const int r = i >> 5;
    const int c = (i & 31) << 2;
    float4 v = make_float4(0.f, 0.f, 0.f, 0.f);
    if (r < nrow) v = *(const float4*)(X + (size_t)(row0 + r) * Dd + c);
    *(float4*)(&S[r * Dd + (c ^ ((r & 3) << 3))]) = v;
  }
  __syncthreads();

  const int ng = t & 15;
  const int mg = t >> 4;
  const int n0 = ng * 8;
  const int sw = (mg & 3) << 3;

  float acc[8][8];
  #pragma unroll
  for (int i = 0; i < 8; ++i)
    #pragma unroll
    for (int j = 0; j < 8; ++j) acc[i][j] = 0.f;
  GEMM_LAYER(W1);
  __syncthreads();

  {
    const float4 b0 = *(const float4*)(B1 + n0);
    const float4 b1 = *(const float4*)(B1 + n0 + 4);
    #pragma unroll
    for (int i = 0; i < 8; ++i) {
      const int m = mg + 16 * i;
      float4 h0, h1;
      h0.x = fmaxf(acc[i][0] + b0.x, 0.f);
      h0.y = fmaxf(acc[i][1] + b0.y, 0.f);
      h0.z = fmaxf(acc[i][2] + b0.z, 0.f);
      h0.w = fmaxf(acc[i][3] + b0.w, 0.f);
      h1.x = fmaxf(acc[i][4] + b1.x, 0.f);
      h1.y = fmaxf(acc[i][5] + b1.y, 0.f);
      h1.z = fmaxf(acc[i][6] + b1.z, 0.f);
      h1.w = fmaxf(acc[i][7] + b1.w, 0.f);
      *(float4*)(&S[m * Dd + (n0 ^ sw)]) = h0;
      *(float4*)(&S[m * Dd + ((n0 + 4) ^ sw)]) = h1;
    }
  }
  __syncthreads();

  #pragma unroll
  for (int i = 0; i < 8; ++i)
    #pragma unroll
    for (int j = 0; j < 8; ++j) acc[i][j] = 0.f;
  GEMM_LAYER(W2);

  const float4 c0 = *(const float4*)(B2 + n0);
  const float4 c1 = *(const float4*)(B2 + n0 + 4);
  #pragma unroll
  for (int i = 0; i < 8; ++i) {
    const int r = mg + 16 * i;
    if (r < nrow) {
      const int gr = row0 + r;
      float v[8];
      v[0] = acc[i][0] + c0.x; v[1] = acc[i][1] + c0.y;
      v[2] = acc[i][2] + c0.z; v[3] = acc[i][3] + c0.w;
      v[4] = acc[i][4] + c1.x; v[5] = acc[i][5] + c1.y;
      v[6] = acc[i][6] + c1.z; v[7] = acc[i][7] + c1.w;
      if (final_relu) {
        #pragma unroll
        for (int j = 0; j < 8; ++j) v[j] = fmaxf(v[j], 0.f);
      }
      if (base) {
        if (gr == sink) {
          #pragma unroll
          for (int j = 0; j < 8; ++j) v[j] = 0.f;  // h[sink] = 0
        }
        const float4 e0 = *(const float4*)(base + (size_t)gr * Dd + n0);
        const float4 e1 = *(const float4*)(base + (size_t)gr * Dd + n0 + 4);
        v[0] += e0.x; v[1] += e0.y; v[2] += e0.z; v[3] += e0.w;
        v[4] += e1.x; v[5] += e1.y; v[6] += e1.z; v[7] += e1.w;
      }
      float* op = out + (size_t)gr * out_stride + out_col + n0;
      *(float4*)op = make_float4(v[0], v[1], v[2], v[3]);
      *(float4*)(op + 4) = make_float4(v[4], v[5], v[6], v[7]);
    }
  }
}

// ---------------------------------------------------------------------------
// Edge-level MLP over dst-sorted edges + in-block segment-sum into Z.
// Edges [row0, row0+128) are sorted by destination node. After computing
// relu(msg) rows into LDS, nodes whose whole edge range lies inside the tile
// get a plain float4 store into Z (exclusive owner; Z pre-zeroed); boundary
// nodes (range crosses the tile edge) use scalar atomics (~2 per block).
// ---------------------------------------------------------------------------
__global__ __launch_bounds__(NT) void edge_mlp_seg_kernel(
    const float* __restrict__ X, const int* __restrict__ gsrc,
    const int* __restrict__ sdst, const int* __restrict__ rowptr,
    const float* __restrict__ W1, const float* __restrict__ B1,
    const float* __restrict__ W2, const float* __restrict__ B2,
    float* __restrict__ Z, int nrows)
{
  __shared__ float S[TE * Dd];   // 64 KB
  __shared__ int sd[TE];
  __shared__ int segnode[TE], segbeg[TE], segend[TE];
  __shared__ int nseg;
  const int t = threadIdx.x;
  const int row0 = blockIdx.x * TE;
  const int rem = nrows - row0;
  const int nrow = rem < TE ? rem : TE;

  if (t == 0) nseg = 0;
  if (t < TE && t < nrow) sd[t] = sdst[row0 + t];

  for (int i = t; i < TE * (Dd / 4); i += NT) {
    const int r = i >> 5;
    const int c = (i & 31) << 2;
    float4 v = make_float4(0.f, 0.f, 0.f, 0.f);
    if (r < nrow) {
      const int g = gsrc[row0 + r];
      v = *(const float4*)(X + (size_t)g * Dd + c);
    }
    *(float4*)(&S[r * Dd + (c ^ ((r & 3) << 3))]) = v;
  }
  __syncthreads();

  // Build segment list (runs concurrently with layer-1 GEMM issue; disjoint LDS)
  if (t < nrow) {
    const bool isStart = (t == 0) || (sd[t] != sd[t - 1]);
    if (isStart) {
      int r2 = t + 1;
      while (r2 < nrow && sd[r2] == sd[t]) ++r2;
      const int idx = atomicAdd(&nseg, 1);
      segnode[idx] = sd[t];
      segbeg[idx] = t;
      segend[idx] = r2;
    }
  }

  const int ng = t & 15;
  const int mg = t >> 4;
  const int n0 = ng * 8;
  const int sw = (mg & 3) << 3;

  float acc[8][8];
  #pragma unroll
  for (int i = 0; i < 8; ++i)
    #pragma unroll
    for (int j = 0; j < 8; ++j) acc[i][j] = 0.f;
  GEMM_LAYER(W1);
  __syncthreads();

  {
    const float4 b0 = *(const float4*)(B1 + n0);
    const float4 b1 = *(const float4*)(B1 + n0 + 4);
    #pragma unroll
    for (int i = 0; i < 8; ++i) {
      const int m = mg + 16 * i;
      float4 h0, h1;
      h0.x = fmaxf(acc[i][0] + b0.x, 0.f);
      h0.y = fmaxf(acc[i][1] + b0.y, 0.f);
      h0.z = fmaxf(acc[i][2] + b0.z, 0.f);
      h0.w = fmaxf(acc[i][3] + b0.w, 0.f);
      h1.x = fmaxf(acc[i][4] + b1.x, 0.f);
      h1.y = fmaxf(acc[i][5] + b1.y, 0.f);
      h1.z = fmaxf(acc[i][6] + b1.z, 0.f);
      h1.w = fmaxf(acc[i][7] + b1.w, 0.f);
      *(float4*)(&S[m * Dd + (n0 ^ sw)]) = h0;
      *(float4*)(&S[m * Dd + ((n0 + 4) ^ sw)]) = h1;
    }
  }
  __syncthreads();

  #pragma unroll
  for (int i = 0; i < 8; ++i)
    #pragma unroll
    for (int j = 0; j < 8; ++j) acc[i][j] = 0.f;
  GEMM_LAYER(W2);
  __syncthreads();  // hidden tile fully consumed; safe to overwrite with msg

  // relu(msg) rows -> LDS (same swizzle: row m uses ((m&3)<<3))
  {
    const float4 c0 = *(const float4*)(B2 + n0);
    const float4 c1 = *(const float4*)(B2 + n0 + 4);
    #pragma unroll
    for (int i = 0; i < 8; ++i) {
      const int m = mg + 16 * i;
      float4 h0, h1;
      h0.x = fmaxf(acc[i][0] + c0.x, 0.f);
      h0.y = fmaxf(acc[i][1] + c0.y, 0.f);
      h0.z = fmaxf(acc[i][2] + c0.z, 0.f);
      h0.w = fmaxf(acc[i][3] + c0.w, 0.f);
      h1.x = fmaxf(acc[i][4] + c1.x, 0.f);
      h1.y = fmaxf(acc[i][5] + c1.y, 0.f);
      h1.z = fmaxf(acc[i][6] + c1.z, 0.f);
      h1.w = fmaxf(acc[i][7] + c1.w, 0.f);
      *(float4*)(&S[m * Dd + (n0 ^ sw)]) = h0;
      *(float4*)(&S[m * Dd + ((n0 + 4) ^ sw)]) = h1;
    }
  }
  __syncthreads();

  // Segment-sum: 8 segments in flight (t>>5), 32 float4-chunks per row (t&31)
  const int chunk = t & 31;
  const int c = chunk << 2;
  const int ns = nseg;
  for (int s_ = t >> 5; s_ < ns; s_ += 8) {
    const int node = segnode[s_];
    const int rb = segbeg[s_];
    const int re = segend[s_];
    float4 sum = make_float4(0.f, 0.f, 0.f, 0.f);
    for (int r = rb; r < re; ++r) {
      const float4 v = *(const float4*)(&S[r * Dd + (c ^ ((r & 3) << 3))]);
      sum.x += v.x; sum.y += v.y; sum.z += v.z; sum.w += v.w;
    }
    float* zp = Z + (size_t)node * Dd + c;
    const bool boundary = (rowptr[node] < row0) || (rowptr[node + 1] > row0 + nrow);
    if (boundary) {
      unsafeAtomicAdd(zp + 0, sum.x);
      unsafeAtomicAdd(zp + 1, sum.y);
      unsafeAtomicAdd(zp + 2, sum.z);
      unsafeAtomicAdd(zp + 3, sum.w);
    } else {
      *(float4*)zp = sum;  // exclusive owner; Z pre-zeroed
    }
  }
}

// ---------------------------------------------------------------------------
// CSR build: histogram -> single-block exclusive scan (x2) -> fill
// ---------------------------------------------------------------------------
__global__ void hist_kernel(const int* __restrict__ src, const int* __restrict__ dst,
                            int* __restrict__ deg_f, int* __restrict__ deg_b, int e)
{
  const int i = blockIdx.x * blockDim.x + threadIdx.x;
  if (i < e) {
    atomicAdd(&deg_f[dst[i]], 1);
    atomicAdd(&deg_b[src[i]], 1);
  }
}

__global__ __launch_bounds__(1024) void scan_kernel(
    const int* __restrict__ deg0, int* __restrict__ rp0, int* __restrict__ cur0,
    const int* __restrict__ deg1, int* __restrict__ rp1, int* __restrict__ cur1,
    int n)
{
  const int* deg = blockIdx.x ? deg1 : deg0;
  int* rp  = blockIdx.x ? rp1  : rp0;
  int* cur = blockIdx.x ? cur1 : cur0;
  __shared__ int a[1024], b[1024];
  const int t = threadIdx.x;
  int run = 0;
  for (int base = 0; base < n; base += 1024) {
    const int v = (base + t < n) ? deg[base + t] : 0;
    a[t] = v;
    __syncthreads();
    int* s = a; int* d = b;
    for (int off = 1; off < 1024; off <<= 1) {
      int x = s[t];
      if (t >= off) x += s[t - off];
      d[t] = x;
      __syncthreads();
      int* tmp = s; s = d; d = tmp;
    }
    const int incl = s[t];
    const int tot = s[1023];
    if (base + t < n) { rp[base + t] = run + incl - v; cur[base + t] = run + incl - v; }
    run += tot;
    __syncthreads();  // protect s[] before next iteration's a[t] write
  }
  if (t == 0) rp[n] = run;
}

__global__ void fill_kernel(const int* __restrict__ src, const int* __restrict__ dst,
                            int* __restrict__ cur_f, int* __restrict__ cur_b,
                            int* __restrict__ gsrc_f, int* __restrict__ sdst_f,
                            int* __restrict__ gsrc_b, int* __restrict__ sdst_b, int e)
{
  const int i = blockIdx.x * blockDim.x + threadIdx.x;
  if (i < e) {
    const int s = src[i], d = dst[i];
    const int p = atomicAdd(&cur_f[d], 1);
    gsrc_f[p] = s; sdst_f[p] = d;
    const int q = atomicAdd(&cur_b[s], 1);
    gsrc_b[q] = d; sdst_b[q] = s;
  }
}

// ---------------------------------------------------------------------------
extern "C" void kernel_launch(void* const* d_in, const int* in_sizes, int n_in,
                              void* d_out, int out_size, void* d_ws, size_t ws_size,
                              hipStream_t stream)
{
  const float* feat = (const float*)d_in[0];
  const int*   src  = (const int*)d_in[1];
  const int*   dst  = (const int*)d_in[2];

  const float* W[5][4];
  for (int p = 0; p < 5; ++p)
    for (int q = 0; q < 4; ++q)
      W[p][q] = (const float*)d_in[3 + p * 4 + q];

  // workspace layout (~91 MB)
  float* st = (float*)d_ws;                     // self_trans  [N,D]
  float* y  = st + (size_t)Nn * Dd;             // y state     [N,D]
  float* z  = y  + (size_t)Nn * Dd;             // segment-sum [N,D]
  int* ip        = (int*)(z + (size_t)Nn * Dd);
  int* rowptr_f  = ip;                 ip += Nn + 1;
  int* rowptr_b  = ip;                 ip += Nn + 1;
  int* deg_f     = ip;                 ip += Nn;   // deg_f/deg_b contiguous
  int* deg_b     = ip;                 ip += Nn;
  int* cur_f     = ip;                 ip += Nn;
  int* cur_b     = ip;                 ip += Nn;
  int* gsrc_f    = ip;                 ip += Ee;
  int* sdst_f    = ip;                 ip += Ee;
  int* gsrc_b    = ip;                 ip += Ee;
  int* sdst_b    = ip;                 ip += Ee;
  float* out = (float*)d_out;                   // [N, 2D]

  const int nodeBlocks = (Nn + TE - 1) / TE;    // 391
  const int edgeBlocks = (Ee + TE - 1) / TE;    // 6250
  const int eGrid = (Ee + NT - 1) / NT;         // 3125

  // ---- CSR build (both directions) ----
  hipMemsetAsync(deg_f, 0, (size_t)2 * Nn * sizeof(int), stream);
  hist_kernel<<<eGrid, NT, 0, stream>>>(src, dst, deg_f, deg_b, Ee);
  scan_kernel<<<2, 1024, 0, stream>>>(deg_f, rowptr_f, cur_f,
                                      deg_b, rowptr_b, cur_b, Nn);
  fill_kernel<<<eGrid, NT, 0, stream>>>(src, dst, cur_f, cur_b,
                                        gsrc_f, sdst_f, gsrc_b, sdst_b, Ee);

  // ---- self_trans = fnn(feat; nt), no final relu ----
  node_mlp_kernel<<<nodeBlocks, NT, 0, stream>>>(
      feat, Nn, W[0][0], W[0][1], W[0][2], W[0][3],
      st, Dd, 0, nullptr, -1, 0);

  for (int dir = 0; dir < 2; ++dir) {
    const int* gs = (dir == 0) ? gsrc_f : gsrc_b;
    const int* sd = (dir == 0) ? sdst_f : sdst_b;
    const int* rp = (dir == 0) ? rowptr_f : rowptr_b;
    const int sink = (dir == 0) ? (Nn - 1) : 0;
    const float* const* P = W[(dir == 0) ? 1 : 3];  // edge MLP
    const float* const* U = W[(dir == 0) ? 2 : 4];  // node MLP
    const float* yin = st;
    for (int k = 0; k < Kk; ++k) {
      hipMemsetAsync(z, 0, (size_t)Nn * Dd * sizeof(float), stream);
      edge_mlp_seg_kernel<<<edgeBlocks, NT, 0, stream>>>(
          yin, gs, sd, rp, P[0], P[1], P[2], P[3], z, Ee);
      const bool last = (k == Kk - 1);
      node_mlp_kernel<<<nodeBlocks, NT, 0, stream>>>(
          z, Nn, U[0], U[1], U[2], U[3],
          last ? out : y, last ? 2 * Dd : Dd, last ? (dir ? Dd : 0) : 0,
          st, sink, 1);
      yin = y;
    }
  }
}

// Round 4
// 2308.257 us; speedup vs baseline: 7.8740x; 2.0919x over previous
//
#include <hip/hip_runtime.h>

// Problem constants (reference: N=50000 nodes, E=800000 edges, D=128, K=3)
#define Nn 50000
#define Ee 800000
#define Dd 128
#define Kk 3
#define TE 128   // rows per block tile
#define NT 256   // threads per block (4 waves)

// LDS bf16 tile row stride: 128 + 8 pad -> b128 frag reads spread banks evenly
#define LSTR 136
// LDS f32 message tile row stride
#define FSTR 132

// Per-matrix packed-weight slot: hi[16384] + lo[16384] ushorts
#define WSLOT 32768

typedef short sh8 __attribute__((ext_vector_type(8)));    // 8 bf16 (4 VGPRs)
typedef float f32x4 __attribute__((ext_vector_type(4)));  // MFMA C/D

// Split fp32 into bf16 hi (truncate) + bf16 lo (residual, truncate).
// x ~= hi + lo with rel err ~2^-15; dropped lo*lo MFMA term ~2^-16.
__device__ __forceinline__ ushort bfsplit(float x, float* rem) {
  const unsigned u = __float_as_uint(x);
  *rem = x - __uint_as_float(u & 0xffff0000u);
  return (ushort)(u >> 16);
}
__device__ __forceinline__ ushort bftrunc(float x) {
  return (ushort)(__float_as_uint(x) >> 16);
}

// 128x128x128 layer on MFMA 16x16x32_bf16, split-bf16 (3 products).
// Wave w owns cols [32w,32w+32) = n-tiles nt0, nt0+1; 8 m-tiles; acc[8][2].
// A frag: lane reads A[m=lane&15][k=(lane>>4)*8+j]  (ds_read_b128)
// B frag: packed global, [((nt*4+c)*64+lane)*8+j]   (global 16B/lane)
#define MFMA_LAYER(WH, WL)                                                     \
  {                                                                            \
    _Pragma("unroll")                                                          \
    for (int c = 0; c < 4; ++c) {                                              \
      const sh8 bh0 = *(const sh8*)(WH + (((nt0    ) * 4 + c) * 64 + lane) * 8); \
      const sh8 bh1 = *(const sh8*)(WH + (((nt0 + 1) * 4 + c) * 64 + lane) * 8); \
      const sh8 bl0 = *(const sh8*)(WL + (((nt0    ) * 4 + c) * 64 + lane) * 8); \
      const sh8 bl1 = *(const sh8*)(WL + (((nt0 + 1) * 4 + c) * 64 + lane) * 8); \
      _Pragma("unroll")                                                        \
      for (int mt = 0; mt < 8; ++mt) {                                         \
        const int aoff = (mt * 16 + l15) * LSTR + c * 32 + q8 * 8;             \
        const sh8 ah = *(const sh8*)(Sh + aoff);                               \
        const sh8 al = *(const sh8*)(Sl + aoff);                               \
        acc[mt][0] = __builtin_amdgcn_mfma_f32_16x16x32_bf16(ah, bh0, acc[mt][0], 0, 0, 0); \
        acc[mt][1] = __builtin_amdgcn_mfma_f32_16x16x32_bf16(ah, bh1, acc[mt][1], 0, 0, 0); \
        acc[mt][0] = __builtin_amdgcn_mfma_f32_16x16x32_bf16(al, bh0, acc[mt][0], 0, 0, 0); \
        acc[mt][1] = __builtin_amdgcn_mfma_f32_16x16x32_bf16(al, bh1, acc[mt][1], 0, 0, 0); \
        acc[mt][0] = __builtin_amdgcn_mfma_f32_16x16x32_bf16(ah, bl0, acc[mt][0], 0, 0, 0); \
        acc[mt][1] = __builtin_amdgcn_mfma_f32_16x16x32_bf16(ah, bl1, acc[mt][1], 0, 0, 0); \
      }                                                                        \
    }                                                                          \
  }

#define ZERO_ACC                                                 \
  {                                                              \
    _Pragma("unroll")                                            \
    for (int mt = 0; mt < 8; ++mt) {                             \
      _Pragma("unroll")                                          \
      for (int nl = 0; nl < 2; ++nl) {                           \
        acc[mt][nl][0] = 0.f; acc[mt][nl][1] = 0.f;              \
        acc[mt][nl][2] = 0.f; acc[mt][nl][3] = 0.f;              \
      }                                                          \
    }                                                            \
  }

// hidden = relu(acc + b1) -> split hi/lo back into LDS (C layout -> A layout)
#define HIDDEN_TO_LDS(B1ptr)                                     \
  {                                                              \
    const float b1a = (B1ptr)[w32 + l15];                        \
    const float b1b = (B1ptr)[w32 + 16 + l15];                   \
    _Pragma("unroll")                                            \
    for (int mt = 0; mt < 8; ++mt) {                             \
      _Pragma("unroll")                                          \
      for (int nl = 0; nl < 2; ++nl) {                           \
        const int col = w32 + nl * 16 + l15;                     \
        const float bb = nl ? b1b : b1a;                         \
        _Pragma("unroll")                                        \
        for (int rg = 0; rg < 4; ++rg) {                         \
          const int row = mt * 16 + q8 * 4 + rg;                 \
          const float h = fmaxf(acc[mt][nl][rg] + bb, 0.f);      \
          float rm;                                              \
          const ushort hh = bfsplit(h, &rm);                     \
          const int off = row * LSTR + col;                      \
          Sh[off] = hh;                                          \
          Sl[off] = bftrunc(rm);                                 \
        }                                                        \
      }                                                          \
    }                                                            \
  }

// ---------------------------------------------------------------------------
// Node-level MLP: out = [relu]( fnn(X) ) (+ base, sink-row zeroed)
// ---------------------------------------------------------------------------
__global__ __launch_bounds__(NT) void node_mlp_mfma(
    const float* __restrict__ X, int nrows,
    const ushort* __restrict__ W1h, const ushort* __restrict__ W1l,
    const ushort* __restrict__ W2h, const ushort* __restrict__ W2l,
    const float* __restrict__ B1, const float* __restrict__ B2,
    float* __restrict__ out, int out_stride, int out_col,
    const float* __restrict__ base, int sink, int final_relu)
{
  __shared__ __align__(16) char smem[2 * TE * LSTR * 2];  // 68 KB
  ushort* Sh = (ushort*)smem;
  ushort* Sl = Sh + TE * LSTR;

  const int t = threadIdx.x;
  const int row0 = blockIdx.x * TE;
  const int rem = nrows - row0;
  const int nrow = rem < TE ? rem : TE;

  // stage + split: 4096 float4 chunks over 256 threads
  #pragma unroll
  for (int it = 0; it < 16; ++it) {
    const int i = t + NT * it;
    const int r = i >> 5;
    const int c4 = (i & 31) << 2;
    float4 v = make_float4(0.f, 0.f, 0.f, 0.f);
    if (r < nrow) v = *(const float4*)(X + (size_t)(row0 + r) * Dd + c4);
    ushort4 hv, lv; float rm;
    hv.x = bfsplit(v.x, &rm); lv.x = bftrunc(rm);
    hv.y = bfsplit(v.y, &rm); lv.y = bftrunc(rm);
    hv.z = bfsplit(v.z, &rm); lv.z = bftrunc(rm);
    hv.w = bfsplit(v.w, &rm); lv.w = bftrunc(rm);
    *(ushort4*)(&Sh[r * LSTR + c4]) = hv;
    *(ushort4*)(&Sl[r * LSTR + c4]) = lv;
  }
  __syncthreads();

  const int lane = t & 63;
  const int wave = t >> 6;
  const int l15 = lane & 15;
  const int q8 = lane >> 4;
  const int w32 = wave * 32;
  const int nt0 = wave * 2;

  f32x4 acc[8][2];
  ZERO_ACC;
  MFMA_LAYER(W1h, W1l);
  __syncthreads();
  HIDDEN_TO_LDS(B1);
  __syncthreads();
  ZERO_ACC;
  MFMA_LAYER(W2h, W2l);

  const float b2a = B2[w32 + l15];
  const float b2b = B2[w32 + 16 + l15];
  #pragma unroll
  for (int mt = 0; mt < 8; ++mt) {
    #pragma unroll
    for (int nl = 0; nl < 2; ++nl) {
      const int col = w32 + nl * 16 + l15;
      const float bb = nl ? b2b : b2a;
      #pragma unroll
      for (int rg = 0; rg < 4; ++rg) {
        const int row = mt * 16 + q8 * 4 + rg;
        if (row < nrow) {
          const int gr = row0 + row;
          float v = acc[mt][nl][rg] + bb;
          if (final_relu) v = fmaxf(v, 0.f);
          if (base) {
            if (gr == sink) v = 0.f;  // h[sink] = 0
            v += base[(size_t)gr * Dd + col];
          }
          out[(size_t)gr * out_stride + out_col + col] = v;
        }
      }
    }
  }
}

// ---------------------------------------------------------------------------
// Edge-level MLP over dst-sorted edges + in-block segment-sum into Z.
// ---------------------------------------------------------------------------
__global__ __launch_bounds__(NT) void edge_mlp_mfma(
    const float* __restrict__ X, const int* __restrict__ gsrc,
    const int* __restrict__ sdst, const int* __restrict__ rowptr,
    const ushort* __restrict__ W1h, const ushort* __restrict__ W1l,
    const ushort* __restrict__ W2h, const ushort* __restrict__ W2l,
    const float* __restrict__ B1, const float* __restrict__ B2,
    float* __restrict__ Z, int nrows)
{
  __shared__ __align__(16) char smem[2 * TE * LSTR * 2];  // 68 KB (bf16 x2 / f32 msg)
  ushort* Sh = (ushort*)smem;
  ushort* Sl = Sh + TE * LSTR;
  float* S32 = (float*)smem;  // stride FSTR, overlaps Sh/Sl after layer 2

  __shared__ int sd[TE];
  __shared__ int segnode[TE], segbeg[TE], segend[TE];
  __shared__ int nseg;

  const int t = threadIdx.x;
  const int row0 = blockIdx.x * TE;
  const int rem = nrows - row0;
  const int nrow = rem < TE ? rem : TE;

  if (t == 0) nseg = 0;
  if (t < TE && t < nrow) sd[t] = sdst[row0 + t];

  #pragma unroll
  for (int it = 0; it < 16; ++it) {
    const int i = t + NT * it;
    const int r = i >> 5;
    const int c4 = (i & 31) << 2;
    float4 v = make_float4(0.f, 0.f, 0.f, 0.f);
    if (r < nrow) {
      const int g = gsrc[row0 + r];
      v = *(const float4*)(X + (size_t)g * Dd + c4);
    }
    ushort4 hv, lv; float rm;
    hv.x = bfsplit(v.x, &rm); lv.x = bftrunc(rm);
    hv.y = bfsplit(v.y, &rm); lv.y = bftrunc(rm);
    hv.z = bfsplit(v.z, &rm); lv.z = bftrunc(rm);
    hv.w = bfsplit(v.w, &rm); lv.w = bftrunc(rm);
    *(ushort4*)(&Sh[r * LSTR + c4]) = hv;
    *(ushort4*)(&Sl[r * LSTR + c4]) = lv;
  }
  __syncthreads();

  // segment list (concurrent with layer-1 GEMM; disjoint LDS)
  if (t < nrow) {
    const bool isStart = (t == 0) || (sd[t] != sd[t - 1]);
    if (isStart) {
      int r2 = t + 1;
      while (r2 < nrow && sd[r2] == sd[t]) ++r2;
      const int idx = atomicAdd(&nseg, 1);
      segnode[idx] = sd[t];
      segbeg[idx] = t;
      segend[idx] = r2;
    }
  }

  const int lane = t & 63;
  const int wave = t >> 6;
  const int l15 = lane & 15;
  const int q8 = lane >> 4;
  const int w32 = wave * 32;
  const int nt0 = wave * 2;

  f32x4 acc[8][2];
  ZERO_ACC;
  MFMA_LAYER(W1h, W1l);
  __syncthreads();
  HIDDEN_TO_LDS(B1);
  __syncthreads();
  ZERO_ACC;
  MFMA_LAYER(W2h, W2l);
  __syncthreads();  // hidden fully consumed by all waves; reuse LDS as f32 msg

  // msg = relu(acc + b2) -> S32 (C layout -> row-major)
  {
    const float b2a = B2[w32 + l15];
    const float b2b = B2[w32 + 16 + l15];
    #pragma unroll
    for (int mt = 0; mt < 8; ++mt) {
      #pragma unroll
      for (int nl = 0; nl < 2; ++nl) {
        const int col = w32 + nl * 16 + l15;
        const float bb = nl ? b2b : b2a;
        #pragma unroll
        for (int rg = 0; rg < 4; ++rg) {
          const int row = mt * 16 + q8 * 4 + rg;
          S32[row * FSTR + col] = fmaxf(acc[mt][nl][rg] + bb, 0.f);
        }
      }
    }
  }
  __syncthreads();

  // segment-sum: 8 segments in flight (t>>5), 32 float4 chunks per row (t&31)
  const int c4 = (t & 31) << 2;
  const int ns = nseg;
  for (int s_ = t >> 5; s_ < ns; s_ += 8) {
    const int node = segnode[s_];
    const int rb = segbeg[s_];
    const int re = segend[s_];
    float4 sum = make_float4(0.f, 0.f, 0.f, 0.f);
    for (int r = rb; r < re; ++r) {
      const float4 v = *(const float4*)(&S32[r * FSTR + c4]);
      sum.x += v.x; sum.y += v.y; sum.z += v.z; sum.w += v.w;
    }
    float* zp = Z + (size_t)node * Dd + c4;
    const bool boundary = (rowptr[node] < row0) || (rowptr[node + 1] > row0 + nrow);
    if (boundary) {
      unsafeAtomicAdd(zp + 0, sum.x);
      unsafeAtomicAdd(zp + 1, sum.y);
      unsafeAtomicAdd(zp + 2, sum.z);
      unsafeAtomicAdd(zp + 3, sum.w);
    } else {
      *(float4*)zp = sum;  // exclusive owner; Z pre-zeroed
    }
  }
}

// ---------------------------------------------------------------------------
// Weight packing: 10 matrices (nt,fp,fu,bp,bu x {w1,w2}) -> B-fragment order,
// split hi/lo. Slot per matrix = WSLOT ushorts: hi[16384] then lo[16384].
// Fragment element id = ((nt*4+ch)*64+lane)*8+j  (16384 per matrix) maps to
// W[k][n]: k = ch*32+(lane>>4)*8+j, n = nt*16+(lane&15).
// Decode: j=id&7, lane=(id>>3)&63, ch=(id>>9)&3, nt=id>>11.
// ---------------------------------------------------------------------------
struct WPtrs { const float* w[10]; };

__global__ void pack_w_kernel(WPtrs P, ushort* __restrict__ out)
{
  const int id = blockIdx.x * blockDim.x + threadIdx.x;  // 0..16383
  const int mat = blockIdx.y;
  const int j = id & 7;
  const int lane = (id >> 3) & 63;
  const int ch = (id >> 9) & 3;
  const int nt = id >> 11;
  const int k = ch * 32 + (lane >> 4) * 8 + j;
  const int n = nt * 16 + (lane & 15);
  const float x = P.w[mat][k * Dd + n];
  float rm;
  const ushort h = bfsplit(x, &rm);
  out[(size_t)mat * WSLOT + id] = h;
  out[(size_t)mat * WSLOT + 16384 + id] = bftrunc(rm);
}

// ---------------------------------------------------------------------------
// CSR build: histogram -> single-block scan (x2, cur aliases deg) -> fill
// ---------------------------------------------------------------------------
__global__ void hist_kernel(const int* __restrict__ src, const int* __restrict__ dst,
                            int* __restrict__ deg_f, int* __restrict__ deg_b, int e)
{
  const int i = blockIdx.x * blockDim.x + threadIdx.x;
  if (i < e) {
    atomicAdd(&deg_f[dst[i]], 1);
    atomicAdd(&deg_b[src[i]], 1);
  }
}

__global__ __launch_bounds__(1024) void scan_kernel(
    const int* deg0, int* rp0, int* cur0,
    const int* deg1, int* rp1, int* cur1, int n)
{
  const int* deg = blockIdx.x ? deg1 : deg0;
  int* rp  = blockIdx.x ? rp1  : rp0;
  int* cur = blockIdx.x ? cur1 : cur0;
  __shared__ int a[1024], b[1024];
  const int t = threadIdx.x;
  int run = 0;
  for (int base = 0; base < n; base += 1024) {
    const int v = (base + t < n) ? deg[base + t] : 0;
    a[t] = v;
    __syncthreads();
    int* s = a; int* d = b;
    for (int off = 1; off < 1024; off <<= 1) {
      int x = s[t];
      if (t >= off) x += s[t - off];
      d[t] = x;
      __syncthreads();
      int* tmp = s; s = d; d = tmp;
    }
    const int incl = s[t];
    const int tot = s[1023];
    if (base + t < n) { rp[base + t] = run + incl - v; cur[base + t] = run + incl - v; }
    run += tot;
    __syncthreads();
  }
  if (t == 0) rp[n] = run;
}

__global__ void fill_kernel(const int* __restrict__ src, const int* __restrict__ dst,
                            int* __restrict__ cur_f, int* __restrict__ cur_b,
                            int* __restrict__ gsrc_f, int* __restrict__ sdst_f,
                            int* __restrict__ gsrc_b, int* __restrict__ sdst_b, int e)
{
  const int i = blockIdx.x * blockDim.x + threadIdx.x;
  if (i < e) {
    const int s = src[i], d = dst[i];
    const int p = atomicAdd(&cur_f[d], 1);
    gsrc_f[p] = s; sdst_f[p] = d;
    const int q = atomicAdd(&cur_b[s], 1);
    gsrc_b[q] = d; sdst_b[q] = s;
  }
}

// ---------------------------------------------------------------------------
extern "C" void kernel_launch(void* const* d_in, const int* in_sizes, int n_in,
                              void* d_out, int out_size, void* d_ws, size_t ws_size,
                              hipStream_t stream)
{
  const float* feat = (const float*)d_in[0];
  const int*   src  = (const int*)d_in[1];
  const int*   dst  = (const int*)d_in[2];

  const float* W[5][4];
  for (int p = 0; p < 5; ++p)
    for (int q = 0; q < 4; ++q)
      W[p][q] = (const float*)d_in[3 + p * 4 + q];

  // workspace layout (~91.4 MB)
  float* st = (float*)d_ws;                     // self_trans  [N,D]
  float* y  = st + (size_t)Nn * Dd;             // y state     [N,D]
  float* z  = y  + (size_t)Nn * Dd;             // segment-sum [N,D]
  int* ip        = (int*)(z + (size_t)Nn * Dd);
  int* rowptr_f  = ip;                 ip += Nn + 1;
  int* rowptr_b  = ip;                 ip += Nn + 1;
  int* deg_f     = ip;                 ip += Nn;   // cur_f aliases deg_f
  int* deg_b     = ip;                 ip += Nn;   // cur_b aliases deg_b
  int* gsrc_f    = ip;                 ip += Ee;
  int* sdst_f    = ip;                 ip += Ee;
  int* gsrc_b    = ip;                 ip += Ee;
  int* sdst_b    = ip;                 ip += Ee;
  ushort* Wp = (ushort*)(((uintptr_t)ip + 63) & ~(uintptr_t)63);  // 10*WSLOT ushorts (640KB)
  float* out = (float*)d_out;                   // [N, 2D]

  const int nodeBlocks = (Nn + TE - 1) / TE;    // 391
  const int edgeBlocks = (Ee + TE - 1) / TE;    // 6250
  const int eGrid = (Ee + NT - 1) / NT;         // 3125

  // ---- pack weights into MFMA B-fragment hi/lo layout ----
  WPtrs wp;
  // order: nt_w1, nt_w2, fp_w1, fp_w2, fu_w1, fu_w2, bp_w1, bp_w2, bu_w1, bu_w2
  for (int p = 0; p < 5; ++p) { wp.w[2 * p] = W[p][0]; wp.w[2 * p + 1] = W[p][2]; }
  pack_w_kernel<<<dim3(64, 10), NT, 0, stream>>>(wp, Wp);

  // ---- CSR build (both directions) ----
  hipMemsetAsync(deg_f, 0, (size_t)2 * Nn * sizeof(int), stream);
  hist_kernel<<<eGrid, NT, 0, stream>>>(src, dst, deg_f, deg_b, Ee);
  scan_kernel<<<2, 1024, 0, stream>>>(deg_f, rowptr_f, deg_f,
                                      deg_b, rowptr_b, deg_b, Nn);
  fill_kernel<<<eGrid, NT, 0, stream>>>(src, dst, deg_f, deg_b,
                                        gsrc_f, sdst_f, gsrc_b, sdst_b, Ee);

  #define WH(m) (Wp + (size_t)(m) * WSLOT)
  #define WL(m) (Wp + (size_t)(m) * WSLOT + 16384)

  // ---- self_trans = fnn(feat; nt), no final relu ----
  node_mlp_mfma<<<nodeBlocks, NT, 0, stream>>>(
      feat, Nn, WH(0), WL(0), WH(1), WL(1), W[0][1], W[0][3],
      st, Dd, 0, nullptr, -1, 0);

  for (int dir = 0; dir < 2; ++dir) {
    const int* gs = (dir == 0) ? gsrc_f : gsrc_b;
    const int* sd = (dir == 0) ? sdst_f : sdst_b;
    const int* rp = (dir == 0) ? rowptr_f : rowptr_b;
    const int sink = (dir == 0) ? (Nn - 1) : 0;
    const int pm = (dir == 0) ? 1 : 3;          // edge MLP index (fp / bp)
    const int um = (dir == 0) ? 2 : 4;          // node MLP index (fu / bu)
    const float* pb1 = W[pm][1]; const float* pb2 = W[pm][3];
    const float* ub1 = W[um][1]; const float* ub2 = W[um][3];
    const float* yin = st;
    for (int k = 0; k < Kk; ++k) {
      hipMemsetAsync(z, 0, (size_t)Nn * Dd * sizeof(float), stream);
      edge_mlp_mfma<<<edgeBlocks, NT, 0, stream>>>(
          yin, gs, sd, rp,
          WH(2 * pm), WL(2 * pm), WH(2 * pm + 1), WL(2 * pm + 1),
          pb1, pb2, z, Ee);
      const bool last = (k == Kk - 1);
      node_mlp_mfma<<<nodeBlocks, NT, 0, stream>>>(
          z, Nn, WH(2 * um), WL(2 * um), WH(2 * um + 1), WL(2 * um + 1),
          ub1, ub2,
          last ? out : y, last ? 2 * Dd : Dd, last ? (dir ? Dd : 0) : 0,
          st, sink, 1);
      yin = y;
    }
  }
  #undef WH
  #undef WL
}

// Round 5
// 1247.038 us; speedup vs baseline: 14.5747x; 1.8510x over previous
//
#include <hip/hip_runtime.h>

// Problem constants (reference: N=50000 nodes, E=800000 edges, D=128, K=3)
#define Nn 50000
#define Ee 800000
#define Dd 128
#define Kk 3
#define TE 128   // rows per block tile
#define NT 256   // threads per block (4 waves)

// LDS bf16 tile row stride (ushorts): 128 + 8 pad
#define LSTR 136
// Per-matrix packed-weight slot: hi[16384] + lo[16384] ushorts
#define WSLOT 32768

typedef short sh8 __attribute__((ext_vector_type(8)));    // 8 bf16 (4 VGPRs)
typedef float f32x4 __attribute__((ext_vector_type(4)));  // MFMA C/D

// Split fp32 into bf16 hi (truncate) + bf16 lo (residual, truncate).
__device__ __forceinline__ ushort bfsplit(float x, float* rem) {
  const unsigned u = __float_as_uint(x);
  *rem = x - __uint_as_float(u & 0xffff0000u);
  return (ushort)(u >> 16);
}
__device__ __forceinline__ ushort bftrunc(float x) {
  return (ushort)(__float_as_uint(x) >> 16);
}

// 128x128x128 layer on MFMA 16x16x32_bf16, split-bf16 (3 products).
// Wave w owns cols [32w,32w+32); 8 m-tiles; acc[8][2].
// A frag: lane reads A[m=lane&15][k=(lane>>4)*8+j]  (ds_read_b128 from Sh/Sl)
// B frag: packed global, [((nt*4+c)*64+lane)*8+j]
#define MFMA_LAYER(WH, WL)                                                     \
  {                                                                            \
    _Pragma("unroll")                                                          \
    for (int c = 0; c < 4; ++c) {                                              \
      const sh8 bh0 = *(const sh8*)((WH) + (((nt0    ) * 4 + c) * 64 + lane) * 8); \
      const sh8 bh1 = *(const sh8*)((WH) + (((nt0 + 1) * 4 + c) * 64 + lane) * 8); \
      const sh8 bl0 = *(const sh8*)((WL) + (((nt0    ) * 4 + c) * 64 + lane) * 8); \
      const sh8 bl1 = *(const sh8*)((WL) + (((nt0 + 1) * 4 + c) * 64 + lane) * 8); \
      _Pragma("unroll")                                                        \
      for (int mt = 0; mt < 8; ++mt) {                                         \
        const int aoff = (mt * 16 + l15) * LSTR + c * 32 + q8 * 8;             \
        const sh8 ah = *(const sh8*)(Sh + aoff);                               \
        const sh8 al = *(const sh8*)(Sl + aoff);                               \
        acc[mt][0] = __builtin_amdgcn_mfma_f32_16x16x32_bf16(ah, bh0, acc[mt][0], 0, 0, 0); \
        acc[mt][1] = __builtin_amdgcn_mfma_f32_16x16x32_bf16(ah, bh1, acc[mt][1], 0, 0, 0); \
        acc[mt][0] = __builtin_amdgcn_mfma_f32_16x16x32_bf16(al, bh0, acc[mt][0], 0, 0, 0); \
        acc[mt][1] = __builtin_amdgcn_mfma_f32_16x16x32_bf16(al, bh1, acc[mt][1], 0, 0, 0); \
        acc[mt][0] = __builtin_amdgcn_mfma_f32_16x16x32_bf16(ah, bl0, acc[mt][0], 0, 0, 0); \
        acc[mt][1] = __builtin_amdgcn_mfma_f32_16x16x32_bf16(ah, bl1, acc[mt][1], 0, 0, 0); \
      }                                                                        \
    }                                                                          \
  }

#define ZERO_ACC                                                 \
  {                                                              \
    _Pragma("unroll")                                            \
    for (int mt = 0; mt < 8; ++mt)                               \
      _Pragma("unroll")                                          \
      for (int nl = 0; nl < 2; ++nl) {                           \
        acc[mt][nl][0] = 0.f; acc[mt][nl][1] = 0.f;              \
        acc[mt][nl][2] = 0.f; acc[mt][nl][3] = 0.f;              \
      }                                                          \
  }

// hidden = relu(acc + b1) -> split hi/lo back into LDS (C layout -> A layout)
#define HIDDEN_TO_LDS(B1ptr)                                     \
  {                                                              \
    const float b1a = (B1ptr)[w32 + l15];                        \
    const float b1b = (B1ptr)[w32 + 16 + l15];                   \
    _Pragma("unroll")                                            \
    for (int mt = 0; mt < 8; ++mt)                               \
      _Pragma("unroll")                                          \
      for (int nl = 0; nl < 2; ++nl) {                           \
        const int col = w32 + nl * 16 + l15;                     \
        const float bb = nl ? b1b : b1a;                         \
        _Pragma("unroll")                                        \
        for (int rg = 0; rg < 4; ++rg) {                         \
          const int row = mt * 16 + q8 * 4 + rg;                 \
          const float h = fmaxf(acc[mt][nl][rg] + bb, 0.f);      \
          float rm;                                              \
          const ushort hh = bfsplit(h, &rm);                     \
          const int off = row * LSTR + col;                      \
          Sh[off] = hh;                                          \
          Sl[off] = bftrunc(rm);                                 \
        }                                                        \
      }                                                          \
  }

// stage rows [row0, row0+nrow) of row-major X (stride Dd) into Sh/Sl split
#define STAGE_ROWS(Xptr)                                                       \
  {                                                                            \
    _Pragma("unroll")                                                          \
    for (int it = 0; it < 16; ++it) {                                          \
      const int i = t + NT * it;                                               \
      const int r = i >> 5;                                                    \
      const int c4 = (i & 31) << 2;                                            \
      float4 v = make_float4(0.f, 0.f, 0.f, 0.f);                              \
      if (r < nrow) v = *(const float4*)((Xptr) + (size_t)(row0 + r) * Dd + c4); \
      ushort4 hv, lv; float rm;                                                \
      hv.x = bfsplit(v.x, &rm); lv.x = bftrunc(rm);                            \
      hv.y = bfsplit(v.y, &rm); lv.y = bftrunc(rm);                            \
      hv.z = bfsplit(v.z, &rm); lv.z = bftrunc(rm);                            \
      hv.w = bfsplit(v.w, &rm); lv.w = bftrunc(rm);                            \
      *(ushort4*)(&Sh[r * LSTR + c4]) = hv;                                    \
      *(ushort4*)(&Sl[r * LSTR + c4]) = lv;                                    \
    }                                                                          \
  }

#define MFMA_PRELUDE                                             \
  const int lane = t & 63;                                       \
  const int wave = t >> 6;                                       \
  const int l15 = lane & 15;                                     \
  const int q8 = lane >> 4;                                      \
  const int w32 = wave * 32;                                     \
  const int nt0 = wave * 2;                                      \
  f32x4 acc[8][2];

// Per-direction parameter pack: packed hi bases (lo = +16384) + biases.
struct DirP {
  const ushort *u1, *u2, *p1, *p2;             // upd w1/w2, msg w1/w2 (packed)
  const float *ub1, *ub2, *pb1, *pb2;
};

// ---------------------------------------------------------------------------
// st = fnn(feat; nt), no final relu. Single direction, 391 blocks.
// ---------------------------------------------------------------------------
__global__ __launch_bounds__(NT) void st_kernel(
    const float* __restrict__ X,
    const ushort* __restrict__ W1, const ushort* __restrict__ W2,
    const float* __restrict__ B1, const float* __restrict__ B2,
    float* __restrict__ out)
{
  __shared__ __align__(16) ushort Sbuf[2 * TE * LSTR];  // 69.6 KB
  ushort* Sh = Sbuf;
  ushort* Sl = Sbuf + TE * LSTR;
  const int t = threadIdx.x;
  const int row0 = blockIdx.x * TE;
  const int rem = Nn - row0;
  const int nrow = rem < TE ? rem : TE;

  STAGE_ROWS(X);
  __syncthreads();
  MFMA_PRELUDE;
  ZERO_ACC;
  MFMA_LAYER(W1, W1 + 16384);
  __syncthreads();
  HIDDEN_TO_LDS(B1);
  __syncthreads();
  ZERO_ACC;
  MFMA_LAYER(W2, W2 + 16384);

  const float b2a = B2[w32 + l15];
  const float b2b = B2[w32 + 16 + l15];
  #pragma unroll
  for (int mt = 0; mt < 8; ++mt)
    #pragma unroll
    for (int nl = 0; nl < 2; ++nl) {
      const int col = w32 + nl * 16 + l15;
      const float bb = nl ? b2b : b2a;
      #pragma unroll
      for (int rg = 0; rg < 4; ++rg) {
        const int row = mt * 16 + q8 * 4 + rg;
        if (row < nrow)
          out[(size_t)(row0 + row) * Dd + col] = acc[mt][nl][rg] + bb;
      }
    }
}

// ---------------------------------------------------------------------------
// Round-1 msg: M = relu(fnn(st; p)) per direction. Dual grid (2*391 blocks).
// ---------------------------------------------------------------------------
__global__ __launch_bounds__(NT) void msg0_kernel(
    const float* __restrict__ st,
    float* __restrict__ Mf, float* __restrict__ Mb, int mstride,
    DirP pf, DirP pb, int nhalf)
{
  __shared__ __align__(16) ushort Sbuf[2 * TE * LSTR];
  ushort* Sh = Sbuf;
  ushort* Sl = Sbuf + TE * LSTR;
  const int t = threadIdx.x;
  const int dir = blockIdx.x >= nhalf;
  const int row0 = (blockIdx.x - dir * nhalf) * TE;
  const int rem = Nn - row0;
  const int nrow = rem < TE ? rem : TE;
  const DirP P = dir ? pb : pf;
  float* Mout = dir ? Mb : Mf;

  STAGE_ROWS(st);
  __syncthreads();
  MFMA_PRELUDE;
  ZERO_ACC;
  MFMA_LAYER(P.p1, P.p1 + 16384);
  __syncthreads();
  HIDDEN_TO_LDS(P.pb1);
  __syncthreads();
  ZERO_ACC;
  MFMA_LAYER(P.p2, P.p2 + 16384);

  const float b2a = P.pb2[w32 + l15];
  const float b2b = P.pb2[w32 + 16 + l15];
  #pragma unroll
  for (int mt = 0; mt < 8; ++mt)
    #pragma unroll
    for (int nl = 0; nl < 2; ++nl) {
      const int col = w32 + nl * 16 + l15;
      const float bb = nl ? b2b : b2a;
      #pragma unroll
      for (int rg = 0; rg < 4; ++rg) {
        const int row = mt * 16 + q8 * 4 + rg;
        if (row < nrow)
          Mout[(size_t)(row0 + row) * mstride + col] =
              fmaxf(acc[mt][nl][rg] + bb, 0.f);
      }
    }
}

// ---------------------------------------------------------------------------
// Fused per-round kernel, dual direction (2*391 blocks):
//   z-tile  = CSR gather-sum of Min rows            (atomic-free, exclusive)
//   y-tile  = st + relu(fnn(z; u)), y[sink] handling
//   DO_MSG:   M' = relu(fnn(y; p)) -> Rout          (rounds 1,2)
//   !DO_MSG:  y -> Rout                             (final round -> d_out)
// ---------------------------------------------------------------------------
template <int DO_MSG>
__global__ __launch_bounds__(NT) void aggupdmsg_kernel(
    const float* __restrict__ Min_f, const float* __restrict__ Min_b, int min_stride,
    const int* __restrict__ rp_f, const int* __restrict__ rp_b,
    const int* __restrict__ col_f, const int* __restrict__ col_b,
    const float* __restrict__ st,
    float* __restrict__ Rf, float* __restrict__ Rb, int rstride,
    DirP pf, DirP pb, int nhalf)
{
  __shared__ __align__(16) ushort Sbuf[2 * TE * LSTR];
  ushort* Sh = Sbuf;
  ushort* Sl = Sbuf + TE * LSTR;
  const int t = threadIdx.x;
  const int dir = blockIdx.x >= nhalf;
  const int row0 = (blockIdx.x - dir * nhalf) * TE;
  const int rem = Nn - row0;
  const int nrow = rem < TE ? rem : TE;
  const DirP P = dir ? pb : pf;
  const float* Min = dir ? Min_b : Min_f;
  const int* rp = dir ? rp_b : rp_f;
  const int* col = dir ? col_b : col_f;
  float* Rout = dir ? Rb : Rf;
  const int sink = dir ? 0 : (Nn - 1);

  // ---- phase A: gather-sum z rows. 2 threads per node, 64 cols each. ----
  {
    const int nr = t >> 1;                 // tile row 0..127
    const int cbase = (t & 1) * 64;        // column half
    float4 za[16];
    #pragma unroll
    for (int i = 0; i < 16; ++i) za[i] = make_float4(0.f, 0.f, 0.f, 0.f);
    if (nr < nrow) {
      const int gnode = row0 + nr;
      const int eb = rp[gnode];
      const int ee = rp[gnode + 1];
      int e = eb;
      for (; e + 1 < ee; e += 2) {          // 2 rows in flight: 32 loads
        const float* r0p = Min + (size_t)col[e] * min_stride + cbase;
        const float* r1p = Min + (size_t)col[e + 1] * min_stride + cbase;
        #pragma unroll
        for (int i = 0; i < 16; ++i) {
          const float4 v0 = *(const float4*)(r0p + i * 4);
          const float4 v1 = *(const float4*)(r1p + i * 4);
          za[i].x += v0.x + v1.x; za[i].y += v0.y + v1.y;
          za[i].z += v0.z + v1.z; za[i].w += v0.w + v1.w;
        }
      }
      if (e < ee) {
        const float* r0p = Min + (size_t)col[e] * min_stride + cbase;
        #pragma unroll
        for (int i = 0; i < 16; ++i) {
          const float4 v0 = *(const float4*)(r0p + i * 4);
          za[i].x += v0.x; za[i].y += v0.y; za[i].z += v0.z; za[i].w += v0.w;
        }
      }
    }
    #pragma unroll
    for (int i = 0; i < 16; ++i) {
      ushort4 hv, lv; float rm;
      hv.x = bfsplit(za[i].x, &rm); lv.x = bftrunc(rm);
      hv.y = bfsplit(za[i].y, &rm); lv.y = bftrunc(rm);
      hv.z = bfsplit(za[i].z, &rm); lv.z = bftrunc(rm);
      hv.w = bfsplit(za[i].w, &rm); lv.w = bftrunc(rm);
      const int c4 = cbase + i * 4;
      *(ushort4*)(&Sh[nr * LSTR + c4]) = hv;
      *(ushort4*)(&Sl[nr * LSTR + c4]) = lv;
    }
  }
  __syncthreads();

  MFMA_PRELUDE;

  // ---- phase B: update MLP ----
  ZERO_ACC;
  MFMA_LAYER(P.u1, P.u1 + 16384);
  __syncthreads();
  HIDDEN_TO_LDS(P.ub1);
  __syncthreads();
  ZERO_ACC;
  MFMA_LAYER(P.u2, P.u2 + 16384);

  // y = st + relu(acc + ub2), y[sink-row contribution] zeroed
  {
    const float b2a = P.ub2[w32 + l15];
    const float b2b = P.ub2[w32 + 16 + l15];
    if (DO_MSG) __syncthreads();  // all hidden reads done before overwrite
    #pragma unroll
    for (int mt = 0; mt < 8; ++mt)
      #pragma unroll
      for (int nl = 0; nl < 2; ++nl) {
        const int col = w32 + nl * 16 + l15;
        const float bb = nl ? b2b : b2a;
        #pragma unroll
        for (int rg = 0; rg < 4; ++rg) {
          const int row = mt * 16 + q8 * 4 + rg;
          float v = 0.f;
          if (row < nrow) {
            const int gr = row0 + row;
            v = fmaxf(acc[mt][nl][rg] + bb, 0.f);
            if (gr == sink) v = 0.f;
            v += st[(size_t)gr * Dd + col];
          }
          if (DO_MSG) {
            float rm;
            const ushort hh = bfsplit(v, &rm);
            const int off = row * LSTR + col;
            Sh[off] = hh;
            Sl[off] = bftrunc(rm);
          } else if (row < nrow) {
            Rout[(size_t)(row0 + row) * rstride + col] = v;
          }
        }
      }
  }

  if (DO_MSG) {
    __syncthreads();
    // ---- phase C: msg MLP on y-tile ----
    ZERO_ACC;
    MFMA_LAYER(P.p1, P.p1 + 16384);
    __syncthreads();
    HIDDEN_TO_LDS(P.pb1);
    __syncthreads();
    ZERO_ACC;
    MFMA_LAYER(P.p2, P.p2 + 16384);

    const float b2a = P.pb2[w32 + l15];
    const float b2b = P.pb2[w32 + 16 + l15];
    #pragma unroll
    for (int mt = 0; mt < 8; ++mt)
      #pragma unroll
      for (int nl = 0; nl < 2; ++nl) {
        const int col = w32 + nl * 16 + l15;
        const float bb = nl ? b2b : b2a;
        #pragma unroll
        for (int rg = 0; rg < 4; ++rg) {
          const int row = mt * 16 + q8 * 4 + rg;
          if (row < nrow)
            Rout[(size_t)(row0 + row) * rstride + col] =
                fmaxf(acc[mt][nl][rg] + bb, 0.f);
        }
      }
  }
}

// ---------------------------------------------------------------------------
// Weight packing: matrices -> B-fragment order, split hi/lo.
// Slot = WSLOT ushorts: hi[16384], lo[16384]. id = ((nt*4+ch)*64+lane)*8+j
// maps to W[k][n]: k = ch*32+(lane>>4)*8+j, n = nt*16+(lane&15).
// ---------------------------------------------------------------------------
struct WPtrs { const float* w[10]; };

__global__ void pack_w_kernel(WPtrs P, ushort* __restrict__ out)
{
  const int id = blockIdx.x * blockDim.x + threadIdx.x;  // 0..16383
  const int mat = blockIdx.y;
  const int j = id & 7;
  const int lane = (id >> 3) & 63;
  const int ch = (id >> 9) & 3;
  const int nt = id >> 11;
  const int k = ch * 32 + (lane >> 4) * 8 + j;
  const int n = nt * 16 + (lane & 15);
  const float x = P.w[mat][k * Dd + n];
  float rm;
  const ushort h = bfsplit(x, &rm);
  out[(size_t)mat * WSLOT + id] = h;
  out[(size_t)mat * WSLOT + 16384 + id] = bftrunc(rm);
}

// ---------------------------------------------------------------------------
// CSR build: histogram -> single-block scan (x2, cur aliases deg) -> fill
// ---------------------------------------------------------------------------
__global__ void hist_kernel(const int* __restrict__ src, const int* __restrict__ dst,
                            int* __restrict__ deg_f, int* __restrict__ deg_b, int e)
{
  const int i = blockIdx.x * blockDim.x + threadIdx.x;
  if (i < e) {
    atomicAdd(&deg_f[dst[i]], 1);
    atomicAdd(&deg_b[src[i]], 1);
  }
}

__global__ __launch_bounds__(1024) void scan_kernel(
    const int* deg0, int* rp0, int* cur0,
    const int* deg1, int* rp1, int* cur1, int n)
{
  const int* deg = blockIdx.x ? deg1 : deg0;
  int* rp  = blockIdx.x ? rp1  : rp0;
  int* cur = blockIdx.x ? cur1 : cur0;
  __shared__ int a[1024], b[1024];
  const int t = threadIdx.x;
  int run = 0;
  for (int base = 0; base < n; base += 1024) {
    const int v = (base + t < n) ? deg[base + t] : 0;
    a[t] = v;
    __syncthreads();
    int* s = a; int* d = b;
    for (int off = 1; off < 1024; off <<= 1) {
      int x = s[t];
      if (t >= off) x += s[t - off];
      d[t] = x;
      __syncthreads();
      int* tmp = s; s = d; d = tmp;
    }
    const int incl = s[t];
    const int tot = s[1023];
    if (base + t < n) { rp[base + t] = run + incl - v; cur[base + t] = run + incl - v; }
    run += tot;
    __syncthreads();
  }
  if (t == 0) rp[n] = run;
}

// forward: col_f (src values) grouped by dst; backward: col_b (dst values)
// grouped by src. (reference backward pass gathers y[dst], scatters to src)
__global__ void fill_kernel(const int* __restrict__ src, const int* __restrict__ dst,
                            int* __restrict__ cur_f, int* __restrict__ cur_b,
                            int* __restrict__ col_f, int* __restrict__ col_b, int e)
{
  const int i = blockIdx.x * blockDim.x + threadIdx.x;
  if (i < e) {
    const int s = src[i], d = dst[i];
    col_f[atomicAdd(&cur_f[d], 1)] = s;
    col_b[atomicAdd(&cur_b[s], 1)] = d;
  }
}

// ---------------------------------------------------------------------------
extern "C" void kernel_launch(void* const* d_in, const int* in_sizes, int n_in,
                              void* d_out, int out_size, void* d_ws, size_t ws_size,
                              hipStream_t stream)
{
  const float* feat = (const float*)d_in[0];
  const int*   src  = (const int*)d_in[1];
  const int*   dst  = (const int*)d_in[2];

  const float* W[5][4];
  for (int p = 0; p < 5; ++p)
    for (int q = 0; q < 4; ++q)
      W[p][q] = (const float*)d_in[3 + p * 4 + q];

  // workspace (~85 MB): st + M-ping (f,b) + CSR + packed weights.
  // M-pong lives in d_out's two column-halves (row stride 2*Dd).
  float* st   = (float*)d_ws;                   // [N,D]
  float* Mp_f = st + (size_t)Nn * Dd;           // ping fwd [N,D]
  float* Mp_b = Mp_f + (size_t)Nn * Dd;         // ping bwd [N,D]
  int* ip       = (int*)(Mp_b + (size_t)Nn * Dd);
  int* rp_f     = ip;                 ip += Nn + 1;
  int* rp_b     = ip;                 ip += Nn + 1;
  int* deg_f    = ip;                 ip += Nn;   // cur aliases deg
  int* deg_b    = ip;                 ip += Nn;
  int* col_f    = ip;                 ip += Ee;
  int* col_b    = ip;                 ip += Ee;
  ushort* Wp = (ushort*)(((uintptr_t)ip + 63) & ~(uintptr_t)63);  // 640 KB
  float* out = (float*)d_out;                   // [N, 2D]
  float* Mq_f = out;                            // pong fwd: cols 0..127
  float* Mq_b = out + Dd;                       // pong bwd: cols 128..255

  const int nodeBlocks = (Nn + TE - 1) / TE;    // 391
  const int dualBlocks = 2 * nodeBlocks;        // 782
  const int eGrid = (Ee + NT - 1) / NT;

  // ---- pack weights ----
  WPtrs wpk;  // slots: 2p = W[p].w1, 2p+1 = W[p].w2
  for (int p = 0; p < 5; ++p) { wpk.w[2 * p] = W[p][0]; wpk.w[2 * p + 1] = W[p][2]; }
  pack_w_kernel<<<dim3(64, 10), NT, 0, stream>>>(wpk, Wp);

  // ---- CSR build ----
  hipMemsetAsync(deg_f, 0, (size_t)2 * Nn * sizeof(int), stream);
  hist_kernel<<<eGrid, NT, 0, stream>>>(src, dst, deg_f, deg_b, Ee);
  scan_kernel<<<2, 1024, 0, stream>>>(deg_f, rp_f, deg_f, deg_b, rp_b, deg_b, Nn);
  fill_kernel<<<eGrid, NT, 0, stream>>>(src, dst, deg_f, deg_b, col_f, col_b, Ee);

  #define WS(m) (Wp + (size_t)(m) * WSLOT)
  // fwd: upd = fu (p=2), msg = fp (p=1); bwd: upd = bu (p=4), msg = bp (p=3)
  DirP Pf = { WS(4), WS(5), WS(2), WS(3), W[2][1], W[2][3], W[1][1], W[1][3] };
  DirP Pb = { WS(8), WS(9), WS(6), WS(7), W[4][1], W[4][3], W[3][1], W[3][3] };

  // ---- st = fnn(feat; nt) ----
  st_kernel<<<nodeBlocks, NT, 0, stream>>>(feat, WS(0), WS(1), W[0][1], W[0][3], st);

  // ---- round 1 msg from st -> M ping ----
  msg0_kernel<<<dualBlocks, NT, 0, stream>>>(st, Mp_f, Mp_b, Dd, Pf, Pb, nodeBlocks);

  // ---- round 1: agg+upd+msg, ping -> pong(out) ----
  aggupdmsg_kernel<1><<<dualBlocks, NT, 0, stream>>>(
      Mp_f, Mp_b, Dd, rp_f, rp_b, col_f, col_b, st,
      Mq_f, Mq_b, 2 * Dd, Pf, Pb, nodeBlocks);

  // ---- round 2: agg+upd+msg, pong(out) -> ping ----
  aggupdmsg_kernel<1><<<dualBlocks, NT, 0, stream>>>(
      Mq_f, Mq_b, 2 * Dd, rp_f, rp_b, col_f, col_b, st,
      Mp_f, Mp_b, Dd, Pf, Pb, nodeBlocks);

  // ---- round 3 (final): agg+upd, ping -> y into out column-halves ----
  aggupdmsg_kernel<0><<<dualBlocks, NT, 0, stream>>>(
      Mp_f, Mp_b, Dd, rp_f, rp_b, col_f, col_b, st,
      out, out + Dd, 2 * Dd, Pf, Pb, nodeBlocks);

  #undef WS
}